// Round 11
// baseline (280.494 us; speedup 1.0000x reference)
//
#include <hip/hip_runtime.h>
#include <math.h>

typedef _Float16 half8 __attribute__((ext_vector_type(8)));
typedef _Float16 half4 __attribute__((ext_vector_type(4)));
typedef float f32x4 __attribute__((ext_vector_type(4)));

#define NPTS 262144
#define BM 128
#define NTHREADS 512

// ws layout (shorts): 14 chunk images, each 32 KB, FRAGMENT-contiguous:
//   within chunk: idx = (frag*64 + lane)*8 + e, frag = rb*2 + kb (rb=rowblock/16, kb=kblock/32)
//   row = rb*16 + (lane&15), k = kb*32 + (lane>>4)*8 + e
// A wave's A-fragment (fg, x, ks) is the contiguous 1KB at frag = (fg*4+x)*2+ks -> one
// coalesced global_load_dwordx4 per fragment (lane stride 16B). Then WH [16][256] row-major.
// Chunk stream: c0=W0 | c1..4=W1 | c5..8=W2 h-part | c9=W2 x-part | c10..13=W3.
#define CHUNK_SHORTS 16384
#define WH_OFF (14 * CHUNK_SHORTS)

__device__ __forceinline__ short f2h(float f) {
  _Float16 h = (_Float16)f;
  return __builtin_bit_cast(short, h);
}

__global__ void prep_kernel(const float* __restrict__ W0, const float* __restrict__ W1,
                            const float* __restrict__ W2, const float* __restrict__ W3,
                            const float* __restrict__ Wxyz, const float* __restrict__ Wrot,
                            const float* __restrict__ Wscale, const float* __restrict__ Wop,
                            short* __restrict__ ws) {
  const int stride = gridDim.x * blockDim.x;
  const int t0 = blockIdx.x * blockDim.x + threadIdx.x;
  for (int i = t0; i < 14 * CHUNK_SHORTS; i += stride) {
    const int c = i >> 14;
    const int q = i & 16383;
    const int rb = q >> 10;
    const int kb = (q >> 9) & 1;
    const int lane = (q >> 3) & 63;
    const int e = q & 7;
    const int r = rb * 16 + (lane & 15);
    const int kk = kb * 32 + (lane >> 4) * 8 + e;
    float v = 0.0f;
    if (c == 0)      { if (kk < 60) v = W0[r * 60 + kk]; }
    else if (c <= 4) { v = W1[r * 256 + (c - 1) * 64 + kk]; }
    else if (c <= 8) { v = W2[r * 316 + (c - 5) * 64 + kk]; }
    else if (c == 9) { if (kk < 60) v = W2[r * 316 + 256 + kk]; }
    else             { v = W3[r * 256 + (c - 10) * 64 + kk]; }
    ws[i] = f2h(v);
  }
  for (int i = t0; i < 16 * 256; i += stride) {
    const int j = i >> 8, k = i & 255;
    float v = 0.0f;
    if (j < 3) v = Wxyz[j * 256 + k];
    else if (j < 7) v = Wrot[(j - 3) * 256 + k];
    else if (j < 10) v = Wscale[(j - 7) * 256 + k];
    else if (j == 10) v = Wop[k];
    ws[WH_OFF + i] = f2h(v);
  }
}

// 8 coalesced global loads: A-fragments (x=0..3, ks=0..1) for chunk c into regs.
__device__ __forceinline__ void load_afrags(half8 (&dst)[8], const short* __restrict__ ws,
                                            int c, int fg, int lane) {
  const short* base = ws + c * CHUNK_SHORTS + fg * 4096 + lane * 8;
#pragma unroll
  for (int f = 0; f < 8; ++f) dst[f] = *(const half8*)(base + f * 512);
}

// 8 ds_read_b128: B-fragments (activations) from swizzled LDS.
__device__ __forceinline__ void load_bfrags(half8 (&b)[8], const char* bsrc, int bstride,
                                            int bkbase, int pg, int lr, int lk) {
#pragma unroll
  for (int x = 0; x < 4; ++x)
#pragma unroll
    for (int ks = 0; ks < 2; ++ks) {
      const int m = pg * 64 + x * 16 + lr;
      b[x * 2 + ks] = *(const half8*)(bsrc + m * bstride +
                                      ((bkbase + ks * 64 + lk * 16) ^ ((m & 7) << 4)));
    }
}

// One 64-k chunk: prefetch next chunk's A-frags, read B-frags, 32 MFMA.
__device__ __forceinline__ void chunk_step(f32x4 (&acc)[4][4], half8 (&acur)[8],
                                           half8 (&anxt)[8], bool prefetch, int cnext,
                                           const short* __restrict__ ws,
                                           const char* bsrc, int bstride, int bkbase,
                                           int fg, int pg, int lr, int lk, int lane) {
  if (prefetch) load_afrags(anxt, ws, cnext, fg, lane);
  half8 bf[8];
  load_bfrags(bf, bsrc, bstride, bkbase, pg, lr, lk);
#pragma unroll
  for (int ks = 0; ks < 2; ++ks)
#pragma unroll
    for (int jt = 0; jt < 4; ++jt)
#pragma unroll
      for (int mt = 0; mt < 4; ++mt)
        acc[jt][mt] = __builtin_amdgcn_mfma_f32_16x16x32_f16(acur[jt * 2 + ks],
                                                             bf[mt * 2 + ks],
                                                             acc[jt][mt], 0, 0, 0);
}

__device__ __forceinline__ void zero_acc(f32x4 (&acc)[4][4]) {
#pragma unroll
  for (int jt = 0; jt < 4; ++jt)
#pragma unroll
    for (int mt = 0; mt < 4; ++mt) {
      f32x4 z = {0.f, 0.f, 0.f, 0.f};
      acc[jt][mt] = z;
    }
}

// bias + relu + fp16 pack: lane holds D[j=fg*64+jt*16+lk*4+r][m=pg*64+mt*16+lr].
__device__ __forceinline__ void epilogue(f32x4 (&acc)[4][4], const float* __restrict__ bias,
                                         char* dst, int fg, int pg, int lr, int lk) {
#pragma unroll
  for (int jt = 0; jt < 4; ++jt) {
    const int j0 = fg * 64 + jt * 16 + lk * 4;
    const f32x4 bv = *(const f32x4*)(bias + j0);
#pragma unroll
    for (int mt = 0; mt < 4; ++mt) {
      const int m = pg * 64 + mt * 16 + lr;
      half4 hv;
#pragma unroll
      for (int r = 0; r < 4; ++r) hv[r] = (_Float16)fmaxf(acc[jt][mt][r] + bv[r], 0.f);
      *(half4*)(dst + ((m * 512 + j0 * 2) ^ ((m & 7) << 4))) = hv;
    }
  }
}

__global__ __launch_bounds__(NTHREADS, 2) void deform_kernel(
    const float* __restrict__ xyz, const float* __restrict__ tptr,
    const float* __restrict__ b0, const float* __restrict__ b1,
    const float* __restrict__ b2, const float* __restrict__ b3,
    const float* __restrict__ bxyz, const float* __restrict__ brot,
    const float* __restrict__ bscale, const float* __restrict__ bop,
    const short* __restrict__ ws, float* __restrict__ out) {
  __shared__ __align__(16) short xin[BM * 64];    // 16 KB, stride 128B, XOR-swizzled
  __shared__ __align__(16) short hbuf[BM * 256];  // 64 KB, stride 512B, XOR-swizzled

  const int t = threadIdx.x;
  const int lane = t & 63;
  const int wid = t >> 6;
  const int fg = wid & 3;
  const int pg = wid >> 2;
  const int lr = lane & 15;
  const int lk = lane >> 4;
  const int p0 = blockIdx.x * BM;

  half8 aA[8], aB[8];
  load_afrags(aA, ws, 0, fg, lane);  // chunk-0 weights in flight during encoding

  const float tval = tptr[0];

  // ---- encoding: thread t fills point m = t>>2, d-slots [q*16, q*16+16) ----
  {
    const int m = t >> 2, q = t & 3;
    const int p = p0 + m;
    const float xc[3] = {xyz[p * 3 + 0], xyz[p * 3 + 1], xyz[p * 3 + 2]};
    half8 v0, v1;
#pragma unroll
    for (int dd = 0; dd < 16; ++dd) {
      const int d = q * 16 + dd;
      float v;
      if (d < 3) {
        v = xc[d];
      } else if (d < 39) {
        const int idx = d - 3;
        const int c = idx / 12;
        const int r = idx - c * 12;
        const int e = (r >= 6) ? r - 6 : r;
        const float rev = xc[c] * (0.5f * (float)(1 << e));
        const float fr = rev - floorf(rev);
        v = (r < 6) ? __builtin_amdgcn_sinf(fr) : __builtin_amdgcn_cosf(fr);
      } else if (d == 39) {
        v = tval;
      } else if (d < 60) {
        const int r = d - 40;
        const int e = (r >= 10) ? r - 10 : r;
        const float rev = tval * (0.5f * (float)(1 << e));
        const float fr = rev - floorf(rev);
        v = (r < 10) ? __builtin_amdgcn_sinf(fr) : __builtin_amdgcn_cosf(fr);
      } else {
        v = 0.f;
      }
      const _Float16 hv = (_Float16)v;
      if (dd < 8) v0[dd] = hv; else v1[dd - 8] = hv;
    }
    char* base = (char*)xin;
    *(half8*)(base + ((m * 128 + q * 32) ^ ((m & 7) << 4))) = v0;
    *(half8*)(base + ((m * 128 + q * 32 + 16) ^ ((m & 7) << 4))) = v1;
  }
  __syncthreads();  // xin ready

  f32x4 acc[4][4];
  zero_acc(acc);

  // layer 0: xin (K=64). Epilogue writes hbuf (first touch, no reader yet -> no barrier).
  chunk_step(acc, aA, aB, true, 1, ws, (const char*)xin, 128, 0, fg, pg, lr, lk, lane);
  epilogue(acc, b0, (char*)hbuf, fg, pg, lr, lk);
  zero_acc(acc);
  __syncthreads();  // hbuf written -> readable

  // layer 1: hbuf (K=256), no intra-layer barriers
  chunk_step(acc, aB, aA, true, 2, ws, (const char*)hbuf, 512, 0,   fg, pg, lr, lk, lane);
  chunk_step(acc, aA, aB, true, 3, ws, (const char*)hbuf, 512, 128, fg, pg, lr, lk, lane);
  chunk_step(acc, aB, aA, true, 4, ws, (const char*)hbuf, 512, 256, fg, pg, lr, lk, lane);
  chunk_step(acc, aA, aB, true, 5, ws, (const char*)hbuf, 512, 384, fg, pg, lr, lk, lane);
  __syncthreads();  // all reads of hbuf done
  epilogue(acc, b1, (char*)hbuf, fg, pg, lr, lk);
  zero_acc(acc);
  __syncthreads();

  // layer 2 (skip): hbuf (K=256) + xin (K=64)
  chunk_step(acc, aB, aA, true, 6, ws, (const char*)hbuf, 512, 0,   fg, pg, lr, lk, lane);
  chunk_step(acc, aA, aB, true, 7, ws, (const char*)hbuf, 512, 128, fg, pg, lr, lk, lane);
  chunk_step(acc, aB, aA, true, 8, ws, (const char*)hbuf, 512, 256, fg, pg, lr, lk, lane);
  chunk_step(acc, aA, aB, true, 9, ws, (const char*)hbuf, 512, 384, fg, pg, lr, lk, lane);
  chunk_step(acc, aB, aA, true, 10, ws, (const char*)xin, 128, 0,   fg, pg, lr, lk, lane);
  __syncthreads();
  epilogue(acc, b2, (char*)hbuf, fg, pg, lr, lk);
  zero_acc(acc);
  __syncthreads();

  // layer 3: hbuf (K=256)
  chunk_step(acc, aA, aB, true, 11, ws, (const char*)hbuf, 512, 0,   fg, pg, lr, lk, lane);
  chunk_step(acc, aB, aA, true, 12, ws, (const char*)hbuf, 512, 128, fg, pg, lr, lk, lane);
  chunk_step(acc, aA, aB, true, 13, ws, (const char*)hbuf, 512, 256, fg, pg, lr, lk, lane);
  chunk_step(acc, aB, aA, false, 0, ws, (const char*)hbuf, 512, 384, fg, pg, lr, lk, lane);
  __syncthreads();
  epilogue(acc, b3, (char*)hbuf, fg, pg, lr, lk);
  __syncthreads();

  // ---- heads: WH[16][256] @ h3 ; fg==0 waves cover all 128 points ----
  if (fg == 0) {
    f32x4 hacc[4];
#pragma unroll
    for (int mt = 0; mt < 4; ++mt) {
      f32x4 z = {0.f, 0.f, 0.f, 0.f};
      hacc[mt] = z;
    }
    const short* WH = ws + WH_OFF;
#pragma unroll
    for (int ks = 0; ks < 8; ++ks) {
      const half8 ah = *(const half8*)(WH + lr * 256 + ks * 32 + lk * 8);
#pragma unroll
      for (int mt = 0; mt < 4; ++mt) {
        const int m = pg * 64 + mt * 16 + lr;
        const half8 bh = *(const half8*)((const char*)hbuf +
                                         ((m * 512 + ks * 64 + lk * 16) ^ ((m & 7) << 4)));
        hacc[mt] = __builtin_amdgcn_mfma_f32_16x16x32_f16(ah, bh, hacc[mt], 0, 0, 0);
      }
    }
    float hb[4];
#pragma unroll
    for (int r = 0; r < 4; ++r) {
      const int j = lk * 4 + r;
      hb[r] = (j < 3) ? bxyz[j] : (j < 7) ? brot[j - 3] : (j < 10) ? bscale[j - 7]
              : (j == 10) ? bop[0] : 0.f;
    }
#pragma unroll
    for (int mt = 0; mt < 4; ++mt) {
      const int p = p0 + pg * 64 + mt * 16 + lr;
#pragma unroll
      for (int r = 0; r < 4; ++r) {
        const int j = lk * 4 + r;
        const float v = hacc[mt][r] + hb[r];
        if (j < 3)        out[p * 3 + j] = v;
        else if (j < 7)   out[3 * NPTS + p * 4 + (j - 3)] = v;
        else if (j < 10)  out[7 * NPTS + p * 3 + (j - 7)] = v;
        else if (j == 10) out[10 * NPTS + p] = v;
      }
    }
  }
}

extern "C" void kernel_launch(void* const* d_in, const int* in_sizes, int n_in,
                              void* d_out, int out_size, void* d_ws, size_t ws_size,
                              hipStream_t stream) {
  const float* xyz    = (const float*)d_in[0];
  const float* tptr   = (const float*)d_in[1];
  const float* W0     = (const float*)d_in[2];
  const float* b0     = (const float*)d_in[3];
  const float* W1     = (const float*)d_in[4];
  const float* b1     = (const float*)d_in[5];
  const float* W2     = (const float*)d_in[6];
  const float* b2     = (const float*)d_in[7];
  const float* W3     = (const float*)d_in[8];
  const float* b3     = (const float*)d_in[9];
  const float* Wxyz   = (const float*)d_in[10];
  const float* bxyz   = (const float*)d_in[11];
  const float* Wrot   = (const float*)d_in[12];
  const float* brot   = (const float*)d_in[13];
  const float* Wscale = (const float*)d_in[14];
  const float* bscale = (const float*)d_in[15];
  const float* Wop    = (const float*)d_in[16];
  const float* bop    = (const float*)d_in[17];
  short* ws  = (short*)d_ws;
  float* out = (float*)d_out;

  prep_kernel<<<256, 256, 0, stream>>>(W0, W1, W2, W3, Wxyz, Wrot, Wscale, Wop, ws);
  deform_kernel<<<NPTS / BM, NTHREADS, 0, stream>>>(xyz, tptr, b0, b1, b2, b3,
                                                    bxyz, brot, bscale, bop, ws, out);
}